// Round 5
// baseline (115.173 us; speedup 1.0000x reference)
//
#include <hip/hip_runtime.h>
#include <hip/hip_bf16.h>
#include <math.h>

// ---------------------------------------------------------------------------
// ColorizationNet inference:
//   base[304] = w1[:, :32768] @ x_conv + b1      (split-K, atomic accumulate)
//   per chunk: h1 = relu(base + W1pc @ [4i,4j,chunk16])
//              h2 = relu(W2 @ h1 + b2); out = sigmoid(W3 @ h2 + b3)
// Convs at pre-pool resolution (4x threads), 2x2 pool via shfl_xor, interior
// fast path. chunk_k: 8 chunks/block, w2q float4 stream depth-2 prefetched.
// ---------------------------------------------------------------------------

#define CONV_FLAT 32768
#define H1_  304
#define H2_  176
#define H2P  192            // h2 thread-pad: 3 full waves
#define OUT_ 48
#define CPB  8

// ws layout (float offsets)
#define WS_C1    0          // 8*128*128  = 131072
#define WS_C2    131072     // 16*64*64   = 65536
#define WS_XC    196608     // 32*32*32   = 32768
#define WS_BASE  229376     // 320
#define WS_W1PCT 229696     // 18*304     = 5472
#define WS_W2Q   235168     // 76*192*4   = 58368  (w2 packed [k/4][tpad][4])
#define WS_W3Q   293536     // 44*48*4    = 8448   (w3 packed [k/4][t][4])

// ---------------- conv1 (+ weight prep in tail blocks) ----------------------
__global__ void conv1_prep_k(const float* __restrict__ x, const float* __restrict__ cw,
                             const float* __restrict__ cb, const float* __restrict__ w1,
                             const float* __restrict__ w2, const float* __restrict__ w3,
                             const float* __restrict__ b1, float* __restrict__ out,
                             float* __restrict__ w1pcT, float* __restrict__ w2q,
                             float* __restrict__ w3q, float* __restrict__ base) {
    if (blockIdx.x >= 2048) {   // prep tail: coalesced reads, scattered writes
        int idx = (blockIdx.x - 2048) * 256 + threadIdx.x;
        if (idx < 304 * 176) {                     // w2 row-major [176][304]
            int t = idx / 304, k = idx - t * 304;
            w2q[(k >> 2) * (H2P * 4) + t * 4 + (k & 3)] = w2[idx];
        }
        if (idx < 48 * 176) {                      // w3 row-major [48][176]
            int t = idx / 176, k = idx - t * 176;
            w3q[(k >> 2) * 192 + t * 4 + (k & 3)] = w3[idx];
        }
        if (idx < 304 * 18) {                      // w1[:, 32768+k]
            int t = idx / 18, k = idx - t * 18;
            w1pcT[k * 304 + t] = w1[(size_t)t * 32786 + 32768 + k];
        }
        if (idx < H1_) base[idx] = b1[idx];
        return;
    }
    int idx = blockIdx.x * 256 + threadIdx.x;      // 8*128*128*4
    int sub = idx & 3;
    int p   = idx >> 2;
    int o  = p >> 14;
    int py = (p >> 7) & 127, px = p & 127;
    int y = py * 2 + (sub >> 1), xx = px * 2 + (sub & 1);
    const float* wo = cw + o * 9;
    float k0 = wo[0], k1 = wo[1], k2 = wo[2], k3 = wo[3], k4 = wo[4],
          k5 = wo[5], k6 = wo[6], k7 = wo[7], k8 = wo[8];
    float acc = cb[o];
    if (y > 0 && y < 255 && xx > 0 && xx < 255) {
        const float* r = x + (y - 1) * 256 + (xx - 1);
        acc += r[0]*k0 + r[1]*k1 + r[2]*k2
             + r[256]*k3 + r[257]*k4 + r[258]*k5
             + r[512]*k6 + r[513]*k7 + r[514]*k8;
    } else {
#pragma unroll
        for (int ky = 0; ky < 3; ky++) {
            int sy = y + ky - 1;
            if ((unsigned)sy > 255u) continue;
            const float* row = x + sy * 256;
#pragma unroll
            for (int kx = 0; kx < 3; kx++) {
                int sx = xx + kx - 1;
                if ((unsigned)sx > 255u) continue;
                acc += row[sx] * wo[ky * 3 + kx];
            }
        }
    }
    acc = fmaxf(acc, __shfl_xor(acc, 1, 64));
    acc = fmaxf(acc, __shfl_xor(acc, 2, 64));
    if (sub == 0) out[p] = fmaxf(acc, 0.f);
}

__global__ void conv2_k(const float* __restrict__ in, const float* __restrict__ w,
                        const float* __restrict__ b, float* __restrict__ out) {
    int idx = blockIdx.x * blockDim.x + threadIdx.x;   // 16*64*64*4
    int sub = idx & 3;
    int p   = idx >> 2;
    int o  = p >> 12;
    int py = (p >> 6) & 63, px = p & 63;
    int y = py * 2 + (sub >> 1), xx = px * 2 + (sub & 1);
    float acc = b[o];
    const float* wo = w + o * 72;
    if (y > 0 && y < 127 && xx > 0 && xx < 127) {
        const float* bi = in + (y - 1) * 128 + (xx - 1);
#pragma unroll
        for (int c = 0; c < 8; c++) {
            const float* r  = bi + c * 16384;
            const float* wc = wo + c * 9;
            acc += r[0]*wc[0] + r[1]*wc[1] + r[2]*wc[2]
                 + r[128]*wc[3] + r[129]*wc[4] + r[130]*wc[5]
                 + r[256]*wc[6] + r[257]*wc[7] + r[258]*wc[8];
        }
    } else {
#pragma unroll
        for (int c = 0; c < 8; c++) {
            const float* inc = in + c * 16384;
            const float* wc  = wo + c * 9;
#pragma unroll
            for (int ky = 0; ky < 3; ky++) {
                int sy = y + ky - 1;
                if ((unsigned)sy > 127u) continue;
                const float* row = inc + sy * 128;
#pragma unroll
                for (int kx = 0; kx < 3; kx++) {
                    int sx = xx + kx - 1;
                    if ((unsigned)sx > 127u) continue;
                    acc += row[sx] * wc[ky * 3 + kx];
                }
            }
        }
    }
    acc = fmaxf(acc, __shfl_xor(acc, 1, 64));
    acc = fmaxf(acc, __shfl_xor(acc, 2, 64));
    if (sub == 0) out[p] = fmaxf(acc, 0.f);
}

__global__ void conv3_k(const float* __restrict__ in, const float* __restrict__ w,
                        const float* __restrict__ b, float* __restrict__ out) {
    int idx = blockIdx.x * blockDim.x + threadIdx.x;   // 32*32*32*4
    int sub = idx & 3;
    int p   = idx >> 2;
    int o  = p >> 10;
    int py = (p >> 5) & 31, px = p & 31;
    int y = py * 2 + (sub >> 1), xx = px * 2 + (sub & 1);
    float acc = b[o];
    const float* wo = w + o * 144;
    if (y > 0 && y < 63 && xx > 0 && xx < 63) {
        const float* bi = in + (y - 1) * 64 + (xx - 1);
#pragma unroll
        for (int c = 0; c < 16; c++) {
            const float* r  = bi + c * 4096;
            const float* wc = wo + c * 9;
            acc += r[0]*wc[0] + r[1]*wc[1] + r[2]*wc[2]
                 + r[64]*wc[3] + r[65]*wc[4] + r[66]*wc[5]
                 + r[128]*wc[6] + r[129]*wc[7] + r[130]*wc[8];
        }
    } else {
#pragma unroll
        for (int c = 0; c < 16; c++) {
            const float* inc = in + c * 4096;
            const float* wc  = wo + c * 9;
#pragma unroll
            for (int ky = 0; ky < 3; ky++) {
                int sy = y + ky - 1;
                if ((unsigned)sy > 63u) continue;
                const float* row = inc + sy * 64;
#pragma unroll
                for (int kx = 0; kx < 3; kx++) {
                    int sx = xx + kx - 1;
                    if ((unsigned)sx > 63u) continue;
                    acc += row[sx] * wc[ky * 3 + kx];
                }
            }
        }
    }
    acc = fmaxf(acc, __shfl_xor(acc, 1, 64));
    acc = fmaxf(acc, __shfl_xor(acc, 2, 64));
    if (sub == 0) out[p] = fmaxf(acc, 0.f);   // layout == x_conv flatten [c][y][x]
}

// split-K: base[row] += dot(w1[row, seg], xconv[seg]); base pre-init to b1
#define NSEG 16
#define SEGLEN (CONV_FLAT / NSEG)   // 2048 floats
__global__ void base_acc_k(const float* __restrict__ w1, const float* __restrict__ xconv,
                           float* __restrict__ base) {
    int row = blockIdx.x >> 4;
    int seg = blockIdx.x & 15;
    const float* wr = w1 + (size_t)row * 32786 + seg * SEGLEN;
    const float* xc = xconv + seg * SEGLEN;
    float acc = 0.f;
#pragma unroll
    for (int i = 0; i < 4; i++) {
        int k = 2 * (threadIdx.x + i * 256);
        float a0 = __builtin_nontemporal_load(wr + k);
        float a1 = __builtin_nontemporal_load(wr + k + 1);
        float2 v = *(const float2*)(xc + k);
        acc += a0 * v.x + a1 * v.y;
    }
#pragma unroll
    for (int off = 32; off > 0; off >>= 1)
        acc += __shfl_down(acc, off, 64);
    __shared__ float red[4];
    int lane = threadIdx.x & 63, wid = threadIdx.x >> 6;
    if (lane == 0) red[wid] = acc;
    __syncthreads();
    if (threadIdx.x == 0)
        atomicAdd(&base[row], red[0] + red[1] + red[2] + red[3]);
}

// fused per-chunk MLP, 8 chunks/block, 512 blocks
__global__ __launch_bounds__(256, 4)
void chunk_k(const float* __restrict__ x, const float* __restrict__ base,
             const float* __restrict__ w1pcT, const float* __restrict__ w2q,
             const float* __restrict__ b2, const float* __restrict__ w3q,
             const float* __restrict__ b3, float* __restrict__ out) {
    __shared__ float pc[CPB][18];
    __shared__ float h1[CPB][H1_];    // rows 1216B, 16B aligned
    __shared__ float h2s[CPB][H2_];   // rows 704B, 16B aligned
    int tid = threadIdx.x;
    int c0 = blockIdx.x * CPB;

    if (tid < CPB * 18) {
        int u = tid / 18, k = tid - u * 18;
        int c = c0 + u;
        int i = c >> 6, j = c & 63;
        float v;
        if (k == 0)      v = (float)(i * 4);
        else if (k == 1) v = (float)(j * 4);
        else {
            int kk = k - 2;
            int r = kk >> 2, cc = kk & 3;
            v = x[(i * 4 + r) * 256 + j * 4 + cc];
        }
        pc[u][k] = v;
    }
    __syncthreads();

    // h1: 304 outputs x 8 chunks
    for (int t = tid; t < H1_; t += 256) {
        float bb = base[t];
        float acc[CPB];
#pragma unroll
        for (int u = 0; u < CPB; u++) acc[u] = bb;
#pragma unroll
        for (int k = 0; k < 18; k++) {
            float w = w1pcT[k * H1_ + t];
#pragma unroll
            for (int u = 0; u < CPB; u++) acc[u] += w * pc[u][k];
        }
#pragma unroll
        for (int u = 0; u < CPB; u++) h1[u][t] = fmaxf(acc[u], 0.f);
    }
    __syncthreads();

    // h2: 176(+16 pad) outputs x 8 chunks; w2q float4 stream, depth-2 prefetch
    if (tid < H2P) {
        const float4* wq = (const float4*)w2q;   // [76][192]
        float bb = (tid < H2_) ? b2[tid] : 0.f;
        float acc[CPB];
#pragma unroll
        for (int u = 0; u < CPB; u++) acc[u] = bb;
        float4 wa = wq[tid];
        float4 wb = wq[H2P + tid];
        for (int g = 0; g < 76; g++) {
            float4 wn = (g < 74) ? wq[(g + 2) * H2P + tid] : wa;
#pragma unroll
            for (int u = 0; u < CPB; u++) {
                float4 h = *(const float4*)&h1[u][g * 4];
                acc[u] += wa.x * h.x + wa.y * h.y + wa.z * h.z + wa.w * h.w;
            }
            wa = wb; wb = wn;
        }
        if (tid < H2_) {
#pragma unroll
            for (int u = 0; u < CPB; u++) h2s[u][tid] = fmaxf(acc[u], 0.f);
        }
    }
    __syncthreads();

    // out: 48 outputs x 8 chunks = 384 items
    for (int i = tid; i < CPB * OUT_; i += 256) {
        int u = i / OUT_, t = i - u * OUT_;
        const float4* wq = (const float4*)w3q;   // [44][48]
        float acc = b3[t];
#pragma unroll 4
        for (int g = 0; g < 44; g++) {
            float4 w = wq[g * OUT_ + t];
            float4 h = *(const float4*)&h2s[u][g * 4];
            acc += w.x * h.x + w.y * h.y + w.z * h.z + w.w * h.w;
        }
        out[(size_t)(c0 + u) * OUT_ + t] = 1.f / (1.f + expf(-acc));
    }
}

extern "C" void kernel_launch(void* const* d_in, const int* in_sizes, int n_in,
                              void* d_out, int out_size, void* d_ws, size_t ws_size,
                              hipStream_t stream) {
    const float* x    = (const float*)d_in[0];
    const float* c1_w = (const float*)d_in[1];
    const float* c1_b = (const float*)d_in[2];
    const float* c2_w = (const float*)d_in[3];
    const float* c2_b = (const float*)d_in[4];
    const float* c3_w = (const float*)d_in[5];
    const float* c3_b = (const float*)d_in[6];
    const float* w1   = (const float*)d_in[7];
    const float* b1   = (const float*)d_in[8];
    const float* w2   = (const float*)d_in[9];
    const float* b2   = (const float*)d_in[10];
    const float* w3   = (const float*)d_in[11];
    const float* b3   = (const float*)d_in[12];
    float* out = (float*)d_out;
    float* ws  = (float*)d_ws;

    float* c1o    = ws + WS_C1;
    float* c2o    = ws + WS_C2;
    float* xconv  = ws + WS_XC;
    float* base   = ws + WS_BASE;
    float* w1pcT  = ws + WS_W1PCT;
    float* w2q    = ws + WS_W2Q;
    float* w3q    = ws + WS_W3Q;

    conv1_prep_k<<<2048 + 209, 256, 0, stream>>>(x, c1_w, c1_b, w1, w2, w3, b1,
                                                 c1o, w1pcT, w2q, w3q, base);
    conv2_k<<<1024, 256, 0, stream>>>(c1o, c2_w, c2_b, c2o);
    conv3_k<<<512, 256, 0, stream>>>(c2o, c3_w, c3_b, xconv);
    base_acc_k<<<H1_ * NSEG, 256, 0, stream>>>(w1, xconv, base);
    chunk_k<<<512, 256, 0, stream>>>(x, base, w1pcT, w2q, b2, w3q, b3, out);
}

// Round 6
// 101.408 us; speedup vs baseline: 1.1357x; 1.1357x over previous
//
#include <hip/hip_runtime.h>
#include <hip/hip_bf16.h>
#include <math.h>

// ---------------------------------------------------------------------------
// ColorizationNet inference:
//   base[304] = w1[:, :32768] @ x_conv + b1      (split-K, atomic accumulate)
//   per chunk: h1 = relu(base + W1pc @ [4i,4j,chunk16])
//              h2 = relu(W2 @ h1 + b2); out = sigmoid(W3 @ h2 + b3)
// Convs at pre-pool resolution (4x threads), 2x2 pool via shfl_xor, interior
// fast path. chunk_k: 4 chunks/block, 1024 blocks, depth-4 unrolled prefetch.
// ---------------------------------------------------------------------------

#define CONV_FLAT 32768
#define H1_  304
#define H2_  176
#define H2P  192            // h2 thread-pad: 3 full waves
#define OUT_ 48
#define CPB  4

// ws layout (float offsets)
#define WS_C1    0          // 8*128*128  = 131072
#define WS_C2    131072     // 16*64*64   = 65536
#define WS_XC    196608     // 32*32*32   = 32768
#define WS_BASE  229376     // 320
#define WS_W1PCT 229696     // 18*304     = 5472
#define WS_W2Q   235168     // 76*192*4   = 58368  (w2 packed [k/4][tpad][4])
#define WS_W3Q   293536     // 44*48*4    = 8448   (w3 packed [k/4][t][4])

// ---------------- conv1 (+ weight prep in tail blocks) ----------------------
__global__ void conv1_prep_k(const float* __restrict__ x, const float* __restrict__ cw,
                             const float* __restrict__ cb, const float* __restrict__ w1,
                             const float* __restrict__ w2, const float* __restrict__ w3,
                             const float* __restrict__ b1, float* __restrict__ out,
                             float* __restrict__ w1pcT, float* __restrict__ w2q,
                             float* __restrict__ w3q, float* __restrict__ base) {
    if (blockIdx.x >= 2048) {   // prep tail: coalesced reads, scattered writes
        int idx = (blockIdx.x - 2048) * 256 + threadIdx.x;
        if (idx < 304 * 176) {                     // w2 row-major [176][304]
            int t = idx / 304, k = idx - t * 304;
            w2q[(k >> 2) * (H2P * 4) + t * 4 + (k & 3)] = w2[idx];
        }
        if (idx < 48 * 176) {                      // w3 row-major [48][176]
            int t = idx / 176, k = idx - t * 176;
            w3q[(k >> 2) * 192 + t * 4 + (k & 3)] = w3[idx];
        }
        if (idx < 304 * 18) {                      // w1[:, 32768+k]
            int t = idx / 18, k = idx - t * 18;
            w1pcT[k * 304 + t] = w1[(size_t)t * 32786 + 32768 + k];
        }
        if (idx < H1_) base[idx] = b1[idx];
        return;
    }
    int idx = blockIdx.x * 256 + threadIdx.x;      // 8*128*128*4
    int sub = idx & 3;
    int p   = idx >> 2;
    int o  = p >> 14;
    int py = (p >> 7) & 127, px = p & 127;
    int y = py * 2 + (sub >> 1), xx = px * 2 + (sub & 1);
    const float* wo = cw + o * 9;
    float k0 = wo[0], k1 = wo[1], k2 = wo[2], k3 = wo[3], k4 = wo[4],
          k5 = wo[5], k6 = wo[6], k7 = wo[7], k8 = wo[8];
    float acc = cb[o];
    if (y > 0 && y < 255 && xx > 0 && xx < 255) {
        const float* r = x + (y - 1) * 256 + (xx - 1);
        acc += r[0]*k0 + r[1]*k1 + r[2]*k2
             + r[256]*k3 + r[257]*k4 + r[258]*k5
             + r[512]*k6 + r[513]*k7 + r[514]*k8;
    } else {
#pragma unroll
        for (int ky = 0; ky < 3; ky++) {
            int sy = y + ky - 1;
            if ((unsigned)sy > 255u) continue;
            const float* row = x + sy * 256;
#pragma unroll
            for (int kx = 0; kx < 3; kx++) {
                int sx = xx + kx - 1;
                if ((unsigned)sx > 255u) continue;
                acc += row[sx] * wo[ky * 3 + kx];
            }
        }
    }
    acc = fmaxf(acc, __shfl_xor(acc, 1, 64));
    acc = fmaxf(acc, __shfl_xor(acc, 2, 64));
    if (sub == 0) out[p] = fmaxf(acc, 0.f);
}

__global__ void conv2_k(const float* __restrict__ in, const float* __restrict__ w,
                        const float* __restrict__ b, float* __restrict__ out) {
    int idx = blockIdx.x * blockDim.x + threadIdx.x;   // 16*64*64*4
    int sub = idx & 3;
    int p   = idx >> 2;
    int o  = p >> 12;
    int py = (p >> 6) & 63, px = p & 63;
    int y = py * 2 + (sub >> 1), xx = px * 2 + (sub & 1);
    float acc = b[o];
    const float* wo = w + o * 72;
    if (y > 0 && y < 127 && xx > 0 && xx < 127) {
        const float* bi = in + (y - 1) * 128 + (xx - 1);
#pragma unroll
        for (int c = 0; c < 8; c++) {
            const float* r  = bi + c * 16384;
            const float* wc = wo + c * 9;
            acc += r[0]*wc[0] + r[1]*wc[1] + r[2]*wc[2]
                 + r[128]*wc[3] + r[129]*wc[4] + r[130]*wc[5]
                 + r[256]*wc[6] + r[257]*wc[7] + r[258]*wc[8];
        }
    } else {
#pragma unroll
        for (int c = 0; c < 8; c++) {
            const float* inc = in + c * 16384;
            const float* wc  = wo + c * 9;
#pragma unroll
            for (int ky = 0; ky < 3; ky++) {
                int sy = y + ky - 1;
                if ((unsigned)sy > 127u) continue;
                const float* row = inc + sy * 128;
#pragma unroll
                for (int kx = 0; kx < 3; kx++) {
                    int sx = xx + kx - 1;
                    if ((unsigned)sx > 127u) continue;
                    acc += row[sx] * wc[ky * 3 + kx];
                }
            }
        }
    }
    acc = fmaxf(acc, __shfl_xor(acc, 1, 64));
    acc = fmaxf(acc, __shfl_xor(acc, 2, 64));
    if (sub == 0) out[p] = fmaxf(acc, 0.f);
}

__global__ void conv3_k(const float* __restrict__ in, const float* __restrict__ w,
                        const float* __restrict__ b, float* __restrict__ out) {
    int idx = blockIdx.x * blockDim.x + threadIdx.x;   // 32*32*32*4
    int sub = idx & 3;
    int p   = idx >> 2;
    int o  = p >> 10;
    int py = (p >> 5) & 31, px = p & 31;
    int y = py * 2 + (sub >> 1), xx = px * 2 + (sub & 1);
    float acc = b[o];
    const float* wo = w + o * 144;
    if (y > 0 && y < 63 && xx > 0 && xx < 63) {
        const float* bi = in + (y - 1) * 64 + (xx - 1);
#pragma unroll
        for (int c = 0; c < 16; c++) {
            const float* r  = bi + c * 4096;
            const float* wc = wo + c * 9;
            acc += r[0]*wc[0] + r[1]*wc[1] + r[2]*wc[2]
                 + r[64]*wc[3] + r[65]*wc[4] + r[66]*wc[5]
                 + r[128]*wc[6] + r[129]*wc[7] + r[130]*wc[8];
        }
    } else {
#pragma unroll
        for (int c = 0; c < 16; c++) {
            const float* inc = in + c * 4096;
            const float* wc  = wo + c * 9;
#pragma unroll
            for (int ky = 0; ky < 3; ky++) {
                int sy = y + ky - 1;
                if ((unsigned)sy > 63u) continue;
                const float* row = inc + sy * 64;
#pragma unroll
                for (int kx = 0; kx < 3; kx++) {
                    int sx = xx + kx - 1;
                    if ((unsigned)sx > 63u) continue;
                    acc += row[sx] * wc[ky * 3 + kx];
                }
            }
        }
    }
    acc = fmaxf(acc, __shfl_xor(acc, 1, 64));
    acc = fmaxf(acc, __shfl_xor(acc, 2, 64));
    if (sub == 0) out[p] = fmaxf(acc, 0.f);   // layout == x_conv flatten [c][y][x]
}

// split-K: base[row] += dot(w1[row, seg], xconv[seg]); base pre-init to b1
#define NSEG 32
#define SEGLEN (CONV_FLAT / NSEG)   // 1024 floats
__global__ void base_acc_k(const float* __restrict__ w1, const float* __restrict__ xconv,
                           float* __restrict__ base) {
    int row = blockIdx.x >> 5;
    int seg = blockIdx.x & 31;
    const float* wr = w1 + (size_t)row * 32786 + seg * SEGLEN;
    const float* xc = xconv + seg * SEGLEN;
    float acc = 0.f;
#pragma unroll
    for (int i = 0; i < 2; i++) {
        int k = 2 * (threadIdx.x + i * 256);
        float a0 = __builtin_nontemporal_load(wr + k);
        float a1 = __builtin_nontemporal_load(wr + k + 1);
        float2 v = *(const float2*)(xc + k);
        acc += a0 * v.x + a1 * v.y;
    }
#pragma unroll
    for (int off = 32; off > 0; off >>= 1)
        acc += __shfl_down(acc, off, 64);
    __shared__ float red[4];
    int lane = threadIdx.x & 63, wid = threadIdx.x >> 6;
    if (lane == 0) red[wid] = acc;
    __syncthreads();
    if (threadIdx.x == 0)
        atomicAdd(&base[row], red[0] + red[1] + red[2] + red[3]);
}

// fused per-chunk MLP, 4 chunks/block, 1024 blocks
__global__ __launch_bounds__(256, 4)
void chunk_k(const float* __restrict__ x, const float* __restrict__ base,
             const float* __restrict__ w1pcT, const float* __restrict__ w2q,
             const float* __restrict__ b2, const float* __restrict__ w3q,
             const float* __restrict__ b3, float* __restrict__ out) {
    __shared__ float pc[CPB][18];
    __shared__ float h1[CPB][H1_];    // rows 1216B, 16B aligned
    __shared__ float h2s[CPB][H2_];   // rows 704B, 16B aligned
    int tid = threadIdx.x;
    int c0 = blockIdx.x * CPB;

    if (tid < CPB * 18) {
        int u = tid / 18, k = tid - u * 18;
        int c = c0 + u;
        int i = c >> 6, j = c & 63;
        float v;
        if (k == 0)      v = (float)(i * 4);
        else if (k == 1) v = (float)(j * 4);
        else {
            int kk = k - 2;
            int r = kk >> 2, cc = kk & 3;
            v = x[(i * 4 + r) * 256 + j * 4 + cc];
        }
        pc[u][k] = v;
    }
    __syncthreads();

    // h1: 304 outputs x 4 chunks
    for (int t = tid; t < H1_; t += 256) {
        float bb = base[t];
        float acc[CPB];
#pragma unroll
        for (int u = 0; u < CPB; u++) acc[u] = bb;
#pragma unroll
        for (int k = 0; k < 18; k++) {
            float w = w1pcT[k * H1_ + t];
#pragma unroll
            for (int u = 0; u < CPB; u++) acc[u] += w * pc[u][k];
        }
#pragma unroll
        for (int u = 0; u < CPB; u++) h1[u][t] = fmaxf(acc[u], 0.f);
    }
    __syncthreads();

    // h2: 176(+16 pad) outputs x 4 chunks; depth-4 unrolled prefetch of wq
    if (tid < H2P) {
        const float4* wq = (const float4*)w2q;   // [76][192]
        float bb = (tid < H2_) ? b2[tid] : 0.f;
        float acc[CPB];
#pragma unroll
        for (int u = 0; u < CPB; u++) acc[u] = bb;
        float4 wr0 = wq[0 * H2P + tid];
        float4 wr1 = wq[1 * H2P + tid];
        float4 wr2 = wq[2 * H2P + tid];
        float4 wr3 = wq[3 * H2P + tid];
        for (int g = 0; g < 76; g += 4) {        // 19 iterations
            float4 nx0, nx1, nx2, nx3;
            if (g + 4 < 76) {                    // compile-time per unroll? no:
                nx0 = wq[(g + 4) * H2P + tid];   // single branch per 4-group,
                nx1 = wq[(g + 5) * H2P + tid];   // uniform across wave
                nx2 = wq[(g + 6) * H2P + tid];
                nx3 = wq[(g + 7) * H2P + tid];
            } else { nx0 = nx1 = nx2 = nx3 = wr0; }
#pragma unroll
            for (int u = 0; u < CPB; u++) {
                float4 h0 = *(const float4*)&h1[u][(g + 0) * 4];
                float4 h1v = *(const float4*)&h1[u][(g + 1) * 4];
                float4 h2v = *(const float4*)&h1[u][(g + 2) * 4];
                float4 h3 = *(const float4*)&h1[u][(g + 3) * 4];
                acc[u] += wr0.x * h0.x + wr0.y * h0.y + wr0.z * h0.z + wr0.w * h0.w;
                acc[u] += wr1.x * h1v.x + wr1.y * h1v.y + wr1.z * h1v.z + wr1.w * h1v.w;
                acc[u] += wr2.x * h2v.x + wr2.y * h2v.y + wr2.z * h2v.z + wr2.w * h2v.w;
                acc[u] += wr3.x * h3.x + wr3.y * h3.y + wr3.z * h3.z + wr3.w * h3.w;
            }
            wr0 = nx0; wr1 = nx1; wr2 = nx2; wr3 = nx3;
        }
        if (tid < H2_) {
#pragma unroll
            for (int u = 0; u < CPB; u++) h2s[u][tid] = fmaxf(acc[u], 0.f);
        }
    }
    __syncthreads();

    // out: 48 outputs x 4 chunks = 192 items
    if (tid < CPB * OUT_) {
        int u = tid / OUT_, t = tid - u * OUT_;
        const float4* wq = (const float4*)w3q;   // [44][48]
        float acc = b3[t];
#pragma unroll 4
        for (int g = 0; g < 44; g++) {
            float4 w = wq[g * OUT_ + t];
            float4 h = *(const float4*)&h2s[u][g * 4];
            acc += w.x * h.x + w.y * h.y + w.z * h.z + w.w * h.w;
        }
        out[(size_t)(c0 + u) * OUT_ + t] = 1.f / (1.f + expf(-acc));
    }
}

extern "C" void kernel_launch(void* const* d_in, const int* in_sizes, int n_in,
                              void* d_out, int out_size, void* d_ws, size_t ws_size,
                              hipStream_t stream) {
    const float* x    = (const float*)d_in[0];
    const float* c1_w = (const float*)d_in[1];
    const float* c1_b = (const float*)d_in[2];
    const float* c2_w = (const float*)d_in[3];
    const float* c2_b = (const float*)d_in[4];
    const float* c3_w = (const float*)d_in[5];
    const float* c3_b = (const float*)d_in[6];
    const float* w1   = (const float*)d_in[7];
    const float* b1   = (const float*)d_in[8];
    const float* w2   = (const float*)d_in[9];
    const float* b2   = (const float*)d_in[10];
    const float* w3   = (const float*)d_in[11];
    const float* b3   = (const float*)d_in[12];
    float* out = (float*)d_out;
    float* ws  = (float*)d_ws;

    float* c1o    = ws + WS_C1;
    float* c2o    = ws + WS_C2;
    float* xconv  = ws + WS_XC;
    float* base   = ws + WS_BASE;
    float* w1pcT  = ws + WS_W1PCT;
    float* w2q    = ws + WS_W2Q;
    float* w3q    = ws + WS_W3Q;

    conv1_prep_k<<<2048 + 209, 256, 0, stream>>>(x, c1_w, c1_b, w1, w2, w3, b1,
                                                 c1o, w1pcT, w2q, w3q, base);
    conv2_k<<<1024, 256, 0, stream>>>(c1o, c2_w, c2_b, c2o);
    conv3_k<<<512, 256, 0, stream>>>(c2o, c3_w, c3_b, xconv);
    base_acc_k<<<H1_ * NSEG, 256, 0, stream>>>(w1, xconv, base);
    chunk_k<<<1024, 256, 0, stream>>>(x, base, w1pcT, w2q, b2, w3q, b3, out);
}

// Round 7
// 87.961 us; speedup vs baseline: 1.3094x; 1.1529x over previous
//
#include <hip/hip_runtime.h>
#include <hip/hip_bf16.h>
#include <math.h>

// ---------------------------------------------------------------------------
// ColorizationNet inference:
//   base[304] = w1[:, :32768] @ x_conv + b1      (split-K, atomic accumulate)
//   per chunk: h1 = relu(base + W1pc @ [4i,4j,chunk16])
//              h2 = relu(W2 @ h1 + b2); out = sigmoid(W3 @ h2 + b3)
// Convs at pre-pool resolution (4x threads), 2x2 pool via shfl_xor, interior
// fast path. chunk_k: r3-proven simple structure (CPB=4, unroll-4, no manual
// prefetch — hand-rolled prefetch regressed codegen twice, r5/r6).
// ---------------------------------------------------------------------------

#define CONV_FLAT 32768
#define H1_  304
#define H2_  176
#define OUT_ 48
#define CPB  4

// ws layout (float offsets)
#define WS_C1    0          // 8*128*128  = 131072
#define WS_C2    131072     // 16*64*64   = 65536
#define WS_XC    196608     // 32*32*32   = 32768
#define WS_BASE  229376     // 320
#define WS_W1PCT 229696     // 18*304     = 5472
#define WS_W2Q   235168     // 76*176*4   = 53504  (w2 packed [k/4][t][4])
#define WS_W3Q   288672     // 44*48*4    = 8448   (w3 packed [k/4][t][4])

// ---------------- conv1 (+ weight prep in tail blocks) ----------------------
__global__ void conv1_prep_k(const float* __restrict__ x, const float* __restrict__ cw,
                             const float* __restrict__ cb, const float* __restrict__ w1,
                             const float* __restrict__ w2, const float* __restrict__ w3,
                             const float* __restrict__ b1, float* __restrict__ out,
                             float* __restrict__ w1pcT, float* __restrict__ w2q,
                             float* __restrict__ w3q, float* __restrict__ base) {
    if (blockIdx.x >= 2048) {   // prep tail: coalesced reads, scattered writes
        int idx = (blockIdx.x - 2048) * 256 + threadIdx.x;
        if (idx < 304 * 176) {                     // w2 row-major [176][304]
            int t = idx / 304, k = idx - t * 304;
            w2q[(k >> 2) * (H2_ * 4) + t * 4 + (k & 3)] = w2[idx];
        }
        if (idx < 48 * 176) {                      // w3 row-major [48][176]
            int t = idx / 176, k = idx - t * 176;
            w3q[(k >> 2) * 192 + t * 4 + (k & 3)] = w3[idx];
        }
        if (idx < 304 * 18) {                      // w1[:, 32768+k]
            int t = idx / 18, k = idx - t * 18;
            w1pcT[k * 304 + t] = w1[(size_t)t * 32786 + 32768 + k];
        }
        if (idx < H1_) base[idx] = b1[idx];
        return;
    }
    int idx = blockIdx.x * 256 + threadIdx.x;      // 8*128*128*4
    int sub = idx & 3;
    int p   = idx >> 2;
    int o  = p >> 14;
    int py = (p >> 7) & 127, px = p & 127;
    int y = py * 2 + (sub >> 1), xx = px * 2 + (sub & 1);
    const float* wo = cw + o * 9;
    float k0 = wo[0], k1 = wo[1], k2 = wo[2], k3 = wo[3], k4 = wo[4],
          k5 = wo[5], k6 = wo[6], k7 = wo[7], k8 = wo[8];
    float acc = cb[o];
    if (y > 0 && y < 255 && xx > 0 && xx < 255) {
        const float* r = x + (y - 1) * 256 + (xx - 1);
        acc += r[0]*k0 + r[1]*k1 + r[2]*k2
             + r[256]*k3 + r[257]*k4 + r[258]*k5
             + r[512]*k6 + r[513]*k7 + r[514]*k8;
    } else {
#pragma unroll
        for (int ky = 0; ky < 3; ky++) {
            int sy = y + ky - 1;
            if ((unsigned)sy > 255u) continue;
            const float* row = x + sy * 256;
#pragma unroll
            for (int kx = 0; kx < 3; kx++) {
                int sx = xx + kx - 1;
                if ((unsigned)sx > 255u) continue;
                acc += row[sx] * wo[ky * 3 + kx];
            }
        }
    }
    acc = fmaxf(acc, __shfl_xor(acc, 1, 64));
    acc = fmaxf(acc, __shfl_xor(acc, 2, 64));
    if (sub == 0) out[p] = fmaxf(acc, 0.f);
}

__global__ void conv2_k(const float* __restrict__ in, const float* __restrict__ w,
                        const float* __restrict__ b, float* __restrict__ out) {
    int idx = blockIdx.x * blockDim.x + threadIdx.x;   // 16*64*64*4
    int sub = idx & 3;
    int p   = idx >> 2;
    int o  = p >> 12;
    int py = (p >> 6) & 63, px = p & 63;
    int y = py * 2 + (sub >> 1), xx = px * 2 + (sub & 1);
    float acc = b[o];
    const float* wo = w + o * 72;
    if (y > 0 && y < 127 && xx > 0 && xx < 127) {
        const float* bi = in + (y - 1) * 128 + (xx - 1);
#pragma unroll
        for (int c = 0; c < 8; c++) {
            const float* r  = bi + c * 16384;
            const float* wc = wo + c * 9;
            acc += r[0]*wc[0] + r[1]*wc[1] + r[2]*wc[2]
                 + r[128]*wc[3] + r[129]*wc[4] + r[130]*wc[5]
                 + r[256]*wc[6] + r[257]*wc[7] + r[258]*wc[8];
        }
    } else {
#pragma unroll
        for (int c = 0; c < 8; c++) {
            const float* inc = in + c * 16384;
            const float* wc  = wo + c * 9;
#pragma unroll
            for (int ky = 0; ky < 3; ky++) {
                int sy = y + ky - 1;
                if ((unsigned)sy > 127u) continue;
                const float* row = inc + sy * 128;
#pragma unroll
                for (int kx = 0; kx < 3; kx++) {
                    int sx = xx + kx - 1;
                    if ((unsigned)sx > 127u) continue;
                    acc += row[sx] * wc[ky * 3 + kx];
                }
            }
        }
    }
    acc = fmaxf(acc, __shfl_xor(acc, 1, 64));
    acc = fmaxf(acc, __shfl_xor(acc, 2, 64));
    if (sub == 0) out[p] = fmaxf(acc, 0.f);
}

__global__ void conv3_k(const float* __restrict__ in, const float* __restrict__ w,
                        const float* __restrict__ b, float* __restrict__ out) {
    int idx = blockIdx.x * blockDim.x + threadIdx.x;   // 32*32*32*4
    int sub = idx & 3;
    int p   = idx >> 2;
    int o  = p >> 10;
    int py = (p >> 5) & 31, px = p & 31;
    int y = py * 2 + (sub >> 1), xx = px * 2 + (sub & 1);
    float acc = b[o];
    const float* wo = w + o * 144;
    if (y > 0 && y < 63 && xx > 0 && xx < 63) {
        const float* bi = in + (y - 1) * 64 + (xx - 1);
#pragma unroll
        for (int c = 0; c < 16; c++) {
            const float* r  = bi + c * 4096;
            const float* wc = wo + c * 9;
            acc += r[0]*wc[0] + r[1]*wc[1] + r[2]*wc[2]
                 + r[64]*wc[3] + r[65]*wc[4] + r[66]*wc[5]
                 + r[128]*wc[6] + r[129]*wc[7] + r[130]*wc[8];
        }
    } else {
#pragma unroll
        for (int c = 0; c < 16; c++) {
            const float* inc = in + c * 4096;
            const float* wc  = wo + c * 9;
#pragma unroll
            for (int ky = 0; ky < 3; ky++) {
                int sy = y + ky - 1;
                if ((unsigned)sy > 63u) continue;
                const float* row = inc + sy * 64;
#pragma unroll
                for (int kx = 0; kx < 3; kx++) {
                    int sx = xx + kx - 1;
                    if ((unsigned)sx > 63u) continue;
                    acc += row[sx] * wc[ky * 3 + kx];
                }
            }
        }
    }
    acc = fmaxf(acc, __shfl_xor(acc, 1, 64));
    acc = fmaxf(acc, __shfl_xor(acc, 2, 64));
    if (sub == 0) out[p] = fmaxf(acc, 0.f);   // layout == x_conv flatten [c][y][x]
}

// split-K: base[row] += dot(w1[row, seg], xconv[seg]); base pre-init to b1
#define NSEG 16
#define SEGLEN (CONV_FLAT / NSEG)   // 2048 floats
__global__ void base_acc_k(const float* __restrict__ w1, const float* __restrict__ xconv,
                           float* __restrict__ base) {
    int row = blockIdx.x >> 4;
    int seg = blockIdx.x & 15;
    const float2* wr = (const float2*)(w1 + (size_t)row * 32786) + seg * (SEGLEN / 2);
    const float2* xc = (const float2*)(xconv) + seg * (SEGLEN / 2);
    float acc = 0.f;
#pragma unroll
    for (int i = 0; i < 4; i++) {
        float2 a = wr[threadIdx.x + i * 256];
        float2 v = xc[threadIdx.x + i * 256];
        acc += a.x * v.x + a.y * v.y;
    }
#pragma unroll
    for (int off = 32; off > 0; off >>= 1)
        acc += __shfl_down(acc, off, 64);
    __shared__ float red[4];
    int lane = threadIdx.x & 63, wid = threadIdx.x >> 6;
    if (lane == 0) red[wid] = acc;
    __syncthreads();
    if (threadIdx.x == 0)
        atomicAdd(&base[row], red[0] + red[1] + red[2] + red[3]);
}

// fused per-chunk MLP, 4 chunks per block, 1024 blocks (r3-proven structure)
__global__ void chunk_k(const float* __restrict__ x, const float* __restrict__ base,
                        const float* __restrict__ w1pcT, const float* __restrict__ w2q,
                        const float* __restrict__ b2, const float* __restrict__ w3q,
                        const float* __restrict__ b3, float* __restrict__ out) {
    __shared__ float pc[CPB][18];
    __shared__ float h1[CPB][H1_];    // rows 1216B, 16B aligned
    __shared__ float h2s[CPB][H2_];   // rows 704B, 16B aligned
    int tid = threadIdx.x;
    int c0 = blockIdx.x * CPB;

    if (tid < CPB * 18) {
        int u = tid / 18, k = tid - u * 18;
        int c = c0 + u;
        int i = c >> 6, j = c & 63;
        float v;
        if (k == 0)      v = (float)(i * 4);
        else if (k == 1) v = (float)(j * 4);
        else {
            int kk = k - 2;
            int r = kk >> 2, cc = kk & 3;
            v = x[(i * 4 + r) * 256 + j * 4 + cc];
        }
        pc[u][k] = v;
    }
    __syncthreads();

    // h1: 304 outputs x 4 chunks
    for (int t = tid; t < H1_; t += 256) {
        float bb = base[t];
        float acc[CPB];
#pragma unroll
        for (int u = 0; u < CPB; u++) acc[u] = bb;
#pragma unroll
        for (int k = 0; k < 18; k++) {
            float w = w1pcT[k * H1_ + t];
#pragma unroll
            for (int u = 0; u < CPB; u++) acc[u] += w * pc[u][k];
        }
#pragma unroll
        for (int u = 0; u < CPB; u++) h1[u][t] = fmaxf(acc[u], 0.f);
    }
    __syncthreads();

    // h2: 176 outputs x 4 chunks; w2q float4 coalesced, h1 float4 broadcast
    if (tid < H2_) {
        const float4* wq = (const float4*)w2q;   // [76][176] float4s
        float acc[CPB];
#pragma unroll
        for (int u = 0; u < CPB; u++) acc[u] = b2[tid];
#pragma unroll 4
        for (int g = 0; g < 76; g++) {
            float4 w = wq[g * H2_ + tid];
#pragma unroll
            for (int u = 0; u < CPB; u++) {
                float4 h = *(const float4*)&h1[u][g * 4];
                acc[u] += w.x * h.x + w.y * h.y + w.z * h.z + w.w * h.w;
            }
        }
#pragma unroll
        for (int u = 0; u < CPB; u++) h2s[u][tid] = fmaxf(acc[u], 0.f);
    }
    __syncthreads();

    // out: 48 outputs x 4 chunks = 192 threads; w3q float4 coalesced
    if (tid < CPB * OUT_) {
        int u = tid / OUT_, t = tid - u * OUT_;
        const float4* wq = (const float4*)w3q;   // [44][48] float4s
        float acc = b3[t];
#pragma unroll 4
        for (int g = 0; g < 44; g++) {
            float4 w = wq[g * OUT_ + t];
            float4 h = *(const float4*)&h2s[u][g * 4];
            acc += w.x * h.x + w.y * h.y + w.z * h.z + w.w * h.w;
        }
        out[(size_t)(c0 + u) * OUT_ + t] = 1.f / (1.f + expf(-acc));
    }
}

extern "C" void kernel_launch(void* const* d_in, const int* in_sizes, int n_in,
                              void* d_out, int out_size, void* d_ws, size_t ws_size,
                              hipStream_t stream) {
    const float* x    = (const float*)d_in[0];
    const float* c1_w = (const float*)d_in[1];
    const float* c1_b = (const float*)d_in[2];
    const float* c2_w = (const float*)d_in[3];
    const float* c2_b = (const float*)d_in[4];
    const float* c3_w = (const float*)d_in[5];
    const float* c3_b = (const float*)d_in[6];
    const float* w1   = (const float*)d_in[7];
    const float* b1   = (const float*)d_in[8];
    const float* w2   = (const float*)d_in[9];
    const float* b2   = (const float*)d_in[10];
    const float* w3   = (const float*)d_in[11];
    const float* b3   = (const float*)d_in[12];
    float* out = (float*)d_out;
    float* ws  = (float*)d_ws;

    float* c1o    = ws + WS_C1;
    float* c2o    = ws + WS_C2;
    float* xconv  = ws + WS_XC;
    float* base   = ws + WS_BASE;
    float* w1pcT  = ws + WS_W1PCT;
    float* w2q    = ws + WS_W2Q;
    float* w3q    = ws + WS_W3Q;

    conv1_prep_k<<<2048 + 209, 256, 0, stream>>>(x, c1_w, c1_b, w1, w2, w3, b1,
                                                 c1o, w1pcT, w2q, w3q, base);
    conv2_k<<<1024, 256, 0, stream>>>(c1o, c2_w, c2_b, c2o);
    conv3_k<<<512, 256, 0, stream>>>(c2o, c3_w, c3_b, xconv);
    base_acc_k<<<H1_ * NSEG, 256, 0, stream>>>(w1, xconv, base);
    chunk_k<<<1024, 256, 0, stream>>>(x, base, w1pcT, w2q, b2, w3q, b3, out);
}